// Round 1
// baseline (530.031 us; speedup 1.0000x reference)
//
#include <hip/hip_runtime.h>
#include <math.h>

// Problem constants (from reference): B=4, H=16, L=1024, scales ws={2,4,8}, HIDDEN=32
#define L_DIM 1024
#define BH 64                       // B*H
#define ROWS_PER_TENSOR (BH * L_DIM)  // 65536 rows per attn tensor

// ---------------------------------------------------------------------------
// Kernel 1: per-row stats (mean, std[ddof=1], max, min) over the last dim.
// One 64-lane wave per row; each lane loads 4 x float4 (16 floats), coalesced.
// Rows 0..65535 -> attn_1, 65536..131071 -> attn_2.
// ---------------------------------------------------------------------------
__global__ __launch_bounds__(256) void row_stats_kernel(
    const float* __restrict__ a1, const float* __restrict__ a2,
    float4* __restrict__ stats)
{
    const int wave = (blockIdx.x << 2) | (threadIdx.x >> 6);
    const int lane = threadIdx.x & 63;
    const int t = wave >> 16;                       // which tensor
    const int r = wave & (ROWS_PER_TENSOR - 1);     // row within tensor
    const float* __restrict__ src = t ? a2 : a1;
    const float4* __restrict__ rowp = (const float4*)(src + (size_t)r * L_DIM);

    float s = 0.f, sq = 0.f, mx = -INFINITY, mn = INFINITY;
#pragma unroll
    for (int c = 0; c < 4; ++c) {
        float4 v = rowp[(c << 6) + lane];           // contiguous 1 KiB per wave-instr
        s  += v.x + v.y + v.z + v.w;
        sq += v.x * v.x + v.y * v.y + v.z * v.z + v.w * v.w;
        mx = fmaxf(mx, fmaxf(fmaxf(v.x, v.y), fmaxf(v.z, v.w)));
        mn = fminf(mn, fminf(fminf(v.x, v.y), fminf(v.z, v.w)));
    }
#pragma unroll
    for (int off = 32; off > 0; off >>= 1) {
        s  += __shfl_xor(s,  off, 64);
        sq += __shfl_xor(sq, off, 64);
        mx = fmaxf(mx, __shfl_xor(mx, off, 64));
        mn = fminf(mn, __shfl_xor(mn, off, 64));
    }
    if (lane == 0) {
        const float invL = 1.0f / (float)L_DIM;
        float mean = s * invL;
        float var  = (sq - s * s * invL) * (1.0f / (float)(L_DIM - 1)); // ddof=1
        var = fmaxf(var, 0.f);
        float4 o;
        o.x = mean; o.y = sqrtf(var); o.z = mx; o.w = mn;
        stats[wave] = o;
    }
}

// ---------------------------------------------------------------------------
// Kernel 2: per-(b,h) gate MLPs + fused softmax-weighted combine.
// Weight LDS layout (floats):
//   W1: [0,768)  b1: [768,864)  W2: [864,2400)  b2: [2400,2448)
//   W3: [2448,2496)  b3: [2496,2499)
// Alphas in LDS: scale0 @ [0,512), scale1 @ [512,768), scale2 @ [768,896)
// ---------------------------------------------------------------------------
#define NW_TOTAL 896  // 512 + 256 + 128

__global__ __launch_bounds__(256) void gate_kernel(
    const float4* __restrict__ stats,
    const float* __restrict__ W1, const float* __restrict__ b1,
    const float* __restrict__ W2, const float* __restrict__ b2,
    const float* __restrict__ W3, const float* __restrict__ b3,
    const float* __restrict__ sw,
    float* __restrict__ out)
{
    __shared__ float wts[2499];
    __shared__ float alpha[NW_TOTAL];

    // cooperative weight staging
    for (int i = threadIdx.x; i < 2499; i += 256) {
        float v;
        if (i < 768)        v = W1[i];
        else if (i < 864)   v = b1[i - 768];
        else if (i < 2400)  v = W2[i - 864];
        else if (i < 2448)  v = b2[i - 2400];
        else if (i < 2496)  v = W3[i - 2448];
        else                v = b3[i - 2496];
        wts[i] = v;
    }
    __syncthreads();

    const int bh = blockIdx.x;
    const float4* __restrict__ st1 = stats + (size_t)bh * L_DIM;
    const float4* __restrict__ st2 = stats + ROWS_PER_TENSOR + (size_t)bh * L_DIM;

    for (int idx = threadIdx.x; idx < NW_TOTAL; idx += 256) {
        int s, w, ws, aoff;
        if (idx < 512)       { s = 0; w = idx;       ws = 2; aoff = 0;   }
        else if (idx < 768)  { s = 1; w = idx - 512; ws = 4; aoff = 512; }
        else                 { s = 2; w = idx - 768; ws = 8; aoff = 768; }

        float g[8] = {0.f, 0.f, 0.f, 0.f, 0.f, 0.f, 0.f, 0.f};
        const int r0 = w * ws;
        for (int j = 0; j < ws; ++j) {
            float4 v1 = st1[r0 + j];
            float4 v2 = st2[r0 + j];
            g[0] += v1.x; g[1] += v1.y; g[2] += v1.z; g[3] += v1.w;
            g[4] += v2.x; g[5] += v2.y; g[6] += v2.z; g[7] += v2.w;
        }
        const float inv = 1.0f / (float)ws;
#pragma unroll
        for (int k = 0; k < 8; ++k) g[k] *= inv;

        // MLP 8 -> 32 -> 16 -> 1 (relu, relu, sigmoid)
        float h1[32];
        const float* W1p = wts + s * 256;
        const float* b1p = wts + 768 + s * 32;
#pragma unroll
        for (int o = 0; o < 32; ++o) {
            float acc = b1p[o];
#pragma unroll
            for (int f = 0; f < 8; ++f) acc += W1p[o * 8 + f] * g[f];
            h1[o] = fmaxf(acc, 0.f);
        }
        float h2[16];
        const float* W2p = wts + 864 + s * 512;
        const float* b2p = wts + 2400 + s * 16;
#pragma unroll
        for (int o = 0; o < 16; ++o) {
            float acc = b2p[o];
#pragma unroll
            for (int f = 0; f < 32; ++f) acc += W2p[o * 32 + f] * h1[f];
            h2[o] = fmaxf(acc, 0.f);
        }
        const float* W3p = wts + 2448 + s * 16;
        float acc = wts[2496 + s];
#pragma unroll
        for (int f = 0; f < 16; ++f) acc += W3p[f] * h2[f];
        alpha[aoff + w] = 1.0f / (1.0f + expf(-acc));
    }
    __syncthreads();

    // softmax over the 3 scale weights (stable)
    const float s0 = sw[0], s1 = sw[1], s2 = sw[2];
    const float m = fmaxf(s0, fmaxf(s1, s2));
    const float e0 = expf(s0 - m), e1 = expf(s1 - m), e2 = expf(s2 - m);
    const float einv = 1.0f / (e0 + e1 + e2);
    const float w0 = e0 * einv, w1 = e1 * einv, w2 = e2 * einv;

    float* __restrict__ outp = out + (size_t)bh * L_DIM;
    for (int l = threadIdx.x; l < L_DIM; l += 256) {
        outp[l] = w0 * alpha[l >> 1]
                + w1 * alpha[512 + (l >> 2)]
                + w2 * alpha[768 + (l >> 3)];
    }
}

extern "C" void kernel_launch(void* const* d_in, const int* in_sizes, int n_in,
                              void* d_out, int out_size, void* d_ws, size_t ws_size,
                              hipStream_t stream) {
    const float* attn1 = (const float*)d_in[0];
    const float* attn2 = (const float*)d_in[1];
    const float* W1 = (const float*)d_in[2];
    const float* b1 = (const float*)d_in[3];
    const float* W2 = (const float*)d_in[4];
    const float* b2 = (const float*)d_in[5];
    const float* W3 = (const float*)d_in[6];
    const float* b3 = (const float*)d_in[7];
    const float* sw = (const float*)d_in[8];
    float* out = (float*)d_out;

    float4* stats = (float4*)d_ws;  // 2 * 65536 float4 = 2 MiB

    // Kernel 1: 2*65536 rows, 4 waves (rows) per 256-thread block
    const int n_rows = 2 * ROWS_PER_TENSOR;
    row_stats_kernel<<<n_rows / 4, 256, 0, stream>>>(attn1, attn2, stats);

    // Kernel 2: one block per (b,h)
    gate_kernel<<<BH, 256, 0, stream>>>(stats, W1, b1, W2, b2, W3, b3, sw, out);
}

// Round 3
// 497.739 us; speedup vs baseline: 1.0649x; 1.0649x over previous
//
#include <hip/hip_runtime.h>
#include <math.h>

// Problem constants (from reference): B=4, H=16, L=1024, scales ws={2,4,8}, HIDDEN=32
#define L_DIM 1024
#define BH 64                         // B*H
#define ROWS_PER_TENSOR (BH * L_DIM)  // 65536 rows per attn tensor

// native vector type — __builtin_nontemporal_load requires scalar/native-vector
// pointee (HIP's float4 = HIP_vector_type wrapper is rejected)
typedef float floatx4 __attribute__((ext_vector_type(4)));

// ---------------------------------------------------------------------------
// Kernel 1: per-row stats (mean, std[ddof=1], max, min) over the last dim.
// One 64-lane wave per row; each lane loads 4 x float4 (16 floats), coalesced.
// Rows 0..65535 -> attn_1, 65536..131071 -> attn_2. Nontemporal loads: 512 MB
// streamed once, zero reuse -> don't pollute L2.
// ---------------------------------------------------------------------------
__global__ __launch_bounds__(256) void row_stats_kernel(
    const float* __restrict__ a1, const float* __restrict__ a2,
    float4* __restrict__ stats)
{
    const int wave = (blockIdx.x << 2) | (threadIdx.x >> 6);
    const int lane = threadIdx.x & 63;
    const int t = wave >> 16;                       // which tensor
    const int r = wave & (ROWS_PER_TENSOR - 1);     // row within tensor
    const float* __restrict__ src = t ? a2 : a1;
    const floatx4* __restrict__ rowp = (const floatx4*)(src + (size_t)r * L_DIM);

    float s = 0.f, sq = 0.f, mx = -INFINITY, mn = INFINITY;
#pragma unroll
    for (int c = 0; c < 4; ++c) {
        floatx4 v = __builtin_nontemporal_load(&rowp[(c << 6) + lane]);
        s  += v.x + v.y + v.z + v.w;
        sq += v.x * v.x + v.y * v.y + v.z * v.z + v.w * v.w;
        mx = fmaxf(mx, fmaxf(fmaxf(v.x, v.y), fmaxf(v.z, v.w)));
        mn = fminf(mn, fminf(fminf(v.x, v.y), fminf(v.z, v.w)));
    }
#pragma unroll
    for (int off = 32; off > 0; off >>= 1) {
        s  += __shfl_xor(s,  off, 64);
        sq += __shfl_xor(sq, off, 64);
        mx = fmaxf(mx, __shfl_xor(mx, off, 64));
        mn = fminf(mn, __shfl_xor(mn, off, 64));
    }
    if (lane == 0) {
        const float invL = 1.0f / (float)L_DIM;
        float mean = s * invL;
        float var  = (sq - s * s * invL) * (1.0f / (float)(L_DIM - 1)); // ddof=1
        var = fmaxf(var, 0.f);
        float4 o;
        o.x = mean; o.y = sqrtf(var); o.z = mx; o.w = mn;
        stats[wave] = o;
    }
}

// ---------------------------------------------------------------------------
// Kernel 2: gate MLPs + fused softmax-weighted combine.
// Grid: 256 blocks = (bh, quarter). Each block handles 256 consecutive rows
// (one quarter of L) of one (b,h): 128 ws=2 windows + 64 ws=4 + 32 ws=8 —
// window boundaries all align at multiples of 256, so quarters are
// independent. One thread per window-MLP (224 active / 256).
//
// Weights are NOT staged in LDS: the scale index is made wave-uniform and
// pinned to an SGPR via readfirstlane, so all weight reads compile to s_load
// (scalar K$ path, wave-shared) and the MLP is pure VALU.
// ---------------------------------------------------------------------------
__global__ __launch_bounds__(256) void gate_kernel(
    const float4* __restrict__ stats,
    const float* __restrict__ W1, const float* __restrict__ b1,
    const float* __restrict__ W2, const float* __restrict__ b2,
    const float* __restrict__ W3, const float* __restrict__ b3,
    const float* __restrict__ sw,
    float* __restrict__ out)
{
    __shared__ float alpha[224];   // [0,128): ws=2, [128,192): ws=4, [192,224): ws=8

    const int bh = blockIdx.x >> 2;
    const int l0 = (blockIdx.x & 3) << 8;           // quarter base row
    const int tid = threadIdx.x;

    const float4* __restrict__ st1 = stats + (size_t)bh * L_DIM;
    const float4* __restrict__ st2 = stats + ROWS_PER_TENSOR + (size_t)bh * L_DIM;

    if (tid < 224) {
        int s, ws, r0;
        if (tid < 128)      { s = 0; ws = 2; r0 = l0 + (tid << 1); }
        else if (tid < 192) { s = 1; ws = 4; r0 = l0 + ((tid - 128) << 2); }
        else                { s = 2; ws = 8; r0 = l0 + ((tid - 192) << 3); }

        // s is uniform across each wave's active lanes -> pin to SGPR so the
        // weight addresses are scalar (s_load through K$, not per-lane vmem).
        const int su = __builtin_amdgcn_readfirstlane(s);
        const float* __restrict__ W1p = W1 + su * 256;   // [32][8]
        const float* __restrict__ b1p = b1 + su * 32;
        const float* __restrict__ W2p = W2 + su * 512;   // [16][32]
        const float* __restrict__ b2p = b2 + su * 16;
        const float* __restrict__ W3p = W3 + su * 16;    // [1][16]
        const float  b3v = b3[su];

        float g[8] = {0.f, 0.f, 0.f, 0.f, 0.f, 0.f, 0.f, 0.f};
        for (int j = 0; j < ws; ++j) {
            float4 v1 = st1[r0 + j];
            float4 v2 = st2[r0 + j];
            g[0] += v1.x; g[1] += v1.y; g[2] += v1.z; g[3] += v1.w;
            g[4] += v2.x; g[5] += v2.y; g[6] += v2.z; g[7] += v2.w;
        }
        const float inv = 1.0f / (float)ws;
#pragma unroll
        for (int k = 0; k < 8; ++k) g[k] *= inv;

        // MLP 8 -> 32 -> 16 -> 1 (relu, relu, sigmoid)
        float h1[32];
#pragma unroll
        for (int o = 0; o < 32; ++o) {
            float acc = b1p[o];
#pragma unroll
            for (int f = 0; f < 8; ++f) acc += W1p[o * 8 + f] * g[f];
            h1[o] = fmaxf(acc, 0.f);
        }
        float h2[16];
#pragma unroll
        for (int o = 0; o < 16; ++o) {
            float acc = b2p[o];
#pragma unroll
            for (int f = 0; f < 32; ++f) acc += W2p[o * 32 + f] * h1[f];
            h2[o] = fmaxf(acc, 0.f);
        }
        float acc = b3v;
#pragma unroll
        for (int f = 0; f < 16; ++f) acc += W3p[f] * h2[f];

        alpha[tid] = 1.0f / (1.0f + expf(-acc));
    }
    __syncthreads();

    // softmax over the 3 scale weights (stable); sw is uniform -> s_load
    const float s0 = sw[0], s1 = sw[1], s2 = sw[2];
    const float m = fmaxf(s0, fmaxf(s1, s2));
    const float e0 = expf(s0 - m), e1 = expf(s1 - m), e2 = expf(s2 - m);
    const float einv = 1.0f / (e0 + e1 + e2);
    const float w0 = e0 * einv, w1 = e1 * einv, w2 = e2 * einv;

    // one output per thread: l = l0 + tid
    out[(size_t)bh * L_DIM + l0 + tid] =
          w0 * alpha[tid >> 1]
        + w1 * alpha[128 + (tid >> 2)]
        + w2 * alpha[192 + (tid >> 3)];
}

extern "C" void kernel_launch(void* const* d_in, const int* in_sizes, int n_in,
                              void* d_out, int out_size, void* d_ws, size_t ws_size,
                              hipStream_t stream) {
    const float* attn1 = (const float*)d_in[0];
    const float* attn2 = (const float*)d_in[1];
    const float* W1 = (const float*)d_in[2];
    const float* b1 = (const float*)d_in[3];
    const float* W2 = (const float*)d_in[4];
    const float* b2 = (const float*)d_in[5];
    const float* W3 = (const float*)d_in[6];
    const float* b3 = (const float*)d_in[7];
    const float* sw = (const float*)d_in[8];
    float* out = (float*)d_out;

    float4* stats = (float4*)d_ws;  // 2 * 65536 float4 = 2 MiB

    // Kernel 1: 2*65536 rows, 4 waves (rows) per 256-thread block
    const int n_rows = 2 * ROWS_PER_TENSOR;
    row_stats_kernel<<<n_rows / 4, 256, 0, stream>>>(attn1, attn2, stats);

    // Kernel 2: one block per (bh, quarter)
    gate_kernel<<<BH * 4, 256, 0, stream>>>(stats, W1, b1, W2, b2, W3, b3, sw, out);
}